// Round 3
// baseline (260.973 us; speedup 1.0000x reference)
//
#include <hip/hip_runtime.h>
#include <hip/hip_bf16.h>
#include <cstdint>

// Problem constants
#define BB   16
#define PP   1024
#define EE   768
#define HID  768
#define NH   12
#define DH   64
#define NPB  (PP * EE)          // 786432 elements per batch
#define MROWS (BB * PP)         // 16384

typedef __bf16 bf16_t;
typedef __bf16 bf16x8 __attribute__((ext_vector_type(8)));
typedef float  f32x4  __attribute__((ext_vector_type(4)));

// Async global->LDS 16B DMA. LDS dest must be wave-uniform base + lane*16.
__device__ __forceinline__ void gld16(const void* g, void* l) {
    __builtin_amdgcn_global_load_lds(
        (const __attribute__((address_space(1))) void*)(uintptr_t)g,
        (__attribute__((address_space(3))) void*)(uint32_t)(uintptr_t)l,
        16, 0, 0);
}

// ---------------------------------------------------------------------------
// Stage 1: per-slice partial sums for batch-global LayerNorm stats
// ---------------------------------------------------------------------------
__global__ __launch_bounds__(256) void stats1_kernel(const float* __restrict__ x,
                                                     float* __restrict__ part) {
    int bid = blockIdx.x;
    int b = bid >> 6, s = bid & 63;
    const float4* xp = (const float4*)(x + (size_t)b * NPB + (size_t)s * 12288);
    float sum = 0.f, ss = 0.f;
#pragma unroll
    for (int i = 0; i < 12; ++i) {
        float4 v = xp[i * 256 + threadIdx.x];
        sum += v.x + v.y + v.z + v.w;
        ss  += v.x * v.x + v.y * v.y + v.z * v.z + v.w * v.w;
    }
#pragma unroll
    for (int off = 32; off > 0; off >>= 1) {
        sum += __shfl_down(sum, off, 64);
        ss  += __shfl_down(ss,  off, 64);
    }
    __shared__ float tmp[8];
    int wave = threadIdx.x >> 6, lane = threadIdx.x & 63;
    if (lane == 0) { tmp[wave * 2] = sum; tmp[wave * 2 + 1] = ss; }
    __syncthreads();
    if (threadIdx.x == 0) {
        part[bid * 2]     = tmp[0] + tmp[2] + tmp[4] + tmp[6];
        part[bid * 2 + 1] = tmp[1] + tmp[3] + tmp[5] + tmp[7];
    }
}

// ---------------------------------------------------------------------------
// prep: LDS-tiled weight transposes (coalesced both sides) + stats finalize.
// blocks [0,432): qkvT tiles ; [432,576): lwT tiles ; 576: stats2.
// ---------------------------------------------------------------------------
__global__ __launch_bounds__(256) void prep_kernel(const float* __restrict__ qkvw,
                                                   const float* __restrict__ linw,
                                                   const float* __restrict__ part,
                                                   bf16_t* __restrict__ qkvT,
                                                   bf16_t* __restrict__ lwT,
                                                   float* __restrict__ stats) {
    int bid = blockIdx.x;
    if (bid < 576) {
        __shared__ float lds[64][65];
        const float* src; bf16_t* dst; int r0, c0, W;
        if (bid < 432) {
            int tr = bid / 36, tc = bid - tr * 36;
            r0 = tr * 64; c0 = tc * 64; src = qkvw; W = 2304; dst = qkvT;
        } else {
            int bb = bid - 432;
            int tr = bb / 12, tc = bb - tr * 12;
            r0 = tr * 64; c0 = tc * 64; src = linw; W = 768; dst = lwT;
        }
        int t = threadIdx.x;
        int rr = t >> 4, cc4 = (t & 15) * 4;
#pragma unroll
        for (int j = 0; j < 4; ++j) {
            float4 v = *(const float4*)(src + (size_t)(r0 + rr + j * 16) * W + c0 + cc4);
            lds[rr + j * 16][cc4 + 0] = v.x;
            lds[rr + j * 16][cc4 + 1] = v.y;
            lds[rr + j * 16][cc4 + 2] = v.z;
            lds[rr + j * 16][cc4 + 3] = v.w;
        }
        __syncthreads();
        int cl = t >> 3, rgl = (t & 7) * 8;
#pragma unroll
        for (int jj = 0; jj < 2; ++jj) {
            int c = jj * 32 + cl;
            union { bf16_t h[8]; uint4 u; } o;
#pragma unroll
            for (int k = 0; k < 8; ++k) o.h[k] = (bf16_t)lds[rgl + k][c];
            *(uint4*)(dst + (size_t)(c0 + c) * 768 + r0 + rgl) = o.u;
        }
    } else {
        int wave = threadIdx.x >> 6, lane = threadIdx.x & 63;
#pragma unroll
        for (int j = 0; j < 4; ++j) {
            int b = wave * 4 + j;
            float sum = part[(b * 64 + lane) * 2];
            float ss  = part[(b * 64 + lane) * 2 + 1];
#pragma unroll
            for (int off = 32; off > 0; off >>= 1) {
                sum += __shfl_down(sum, off, 64);
                ss  += __shfl_down(ss,  off, 64);
            }
            if (lane == 0) {
                const float inv_n = 1.f / (float)NPB;
                float mean = sum * inv_n;
                float var  = ss * inv_n - mean * mean;
                stats[b * 2]     = mean;
                stats[b * 2 + 1] = rsqrtf(var + 1e-5f);
            }
        }
    }
}

__global__ __launch_bounds__(256) void ln_apply_kernel(const float* __restrict__ x,
                                                       const float* __restrict__ lnw,
                                                       const float* __restrict__ lnb,
                                                       const float* __restrict__ stats,
                                                       bf16_t* __restrict__ xn) {
    int i = (blockIdx.x * 256 + threadIdx.x) * 8;
    int b = i / NPB;
    int r = i - b * NPB;
    float mean = stats[b * 2], rstd = stats[b * 2 + 1];
    float4 x0 = *(const float4*)(x + i),     x1 = *(const float4*)(x + i + 4);
    float4 w0 = *(const float4*)(lnw + r),   w1 = *(const float4*)(lnw + r + 4);
    float4 c0 = *(const float4*)(lnb + r),   c1 = *(const float4*)(lnb + r + 4);
    union { bf16_t h[8]; uint4 u; } o;
    o.h[0] = (bf16_t)((x0.x - mean) * rstd * w0.x + c0.x);
    o.h[1] = (bf16_t)((x0.y - mean) * rstd * w0.y + c0.y);
    o.h[2] = (bf16_t)((x0.z - mean) * rstd * w0.z + c0.z);
    o.h[3] = (bf16_t)((x0.w - mean) * rstd * w0.w + c0.w);
    o.h[4] = (bf16_t)((x1.x - mean) * rstd * w1.x + c1.x);
    o.h[5] = (bf16_t)((x1.y - mean) * rstd * w1.y + c1.y);
    o.h[6] = (bf16_t)((x1.z - mean) * rstd * w1.z + c1.z);
    o.h[7] = (bf16_t)((x1.w - mean) * rstd * w1.w + c1.w);
    *(uint4*)(xn + i) = o.u;
}

// ---------------------------------------------------------------------------
// Core 128x128 GEMM tile (kept for gemm_out), BK=64, DMA staging.
// ---------------------------------------------------------------------------
template <int KDIM>
__device__ __forceinline__ void gemm_core_128(const bf16_t* __restrict__ A,
                                              const bf16_t* __restrict__ Bt,
                                              int mBase, int nBase,
                                              f32x4 acc[4][4],
                                              bf16_t* As, bf16_t* Bs) {
    const int t = threadIdx.x;
    const int lane = t & 63, wave = t >> 6;
    const int wm = wave >> 1, wn = wave & 1;
    const int m16 = lane & 15, quad = lane >> 4;

    const int sr = t >> 3, s8 = t & 7;
    const bf16_t* pa[4]; const bf16_t* pb[4];
#pragma unroll
    for (int i = 0; i < 4; ++i) {
        int row = i * 32 + sr;
        int g = (s8 - (row & 7)) & 7;
        pa[i] = A  + (size_t)(mBase + row) * KDIM + g * 8;
        pb[i] = Bt + (size_t)(nBase + row) * KDIM + g * 8;
    }

    int raOff[4][2], rbOff[4][2];
#pragma unroll
    for (int i = 0; i < 4; ++i) {
        int ra = wm * 64 + i * 16 + m16;
        int rb = wn * 64 + i * 16 + m16;
#pragma unroll
        for (int ks = 0; ks < 2; ++ks) {
            raOff[i][ks] = ra * 64 + (((ks * 4 + quad) + (ra & 7)) & 7) * 8;
            rbOff[i][ks] = rb * 64 + (((ks * 4 + quad) + (rb & 7)) & 7) * 8;
        }
    }

    const f32x4 z = {0.f, 0.f, 0.f, 0.f};
#pragma unroll
    for (int mm = 0; mm < 4; ++mm)
#pragma unroll
        for (int nn = 0; nn < 4; ++nn) acc[mm][nn] = z;

    for (int k0 = 0; k0 < KDIM; k0 += 64) {
        __syncthreads();
#pragma unroll
        for (int i = 0; i < 4; ++i) {
            gld16(pa[i] + k0, As + i * 2048 + t * 8);
            gld16(pb[i] + k0, Bs + i * 2048 + t * 8);
        }
        __syncthreads();
#pragma unroll
        for (int ks = 0; ks < 2; ++ks) {
            bf16x8 af[4], bfv[4];
#pragma unroll
            for (int i = 0; i < 4; ++i) {
                af[i]  = *(const bf16x8*)(As + raOff[i][ks]);
                bfv[i] = *(const bf16x8*)(Bs + rbOff[i][ks]);
            }
#pragma unroll
            for (int mm = 0; mm < 4; ++mm)
#pragma unroll
                for (int nn = 0; nn < 4; ++nn)
                    acc[mm][nn] = __builtin_amdgcn_mfma_f32_16x16x32_bf16(
                        af[mm], bfv[nn], acc[mm][nn], 0, 0, 0);
        }
    }
}

// ---------------------------------------------------------------------------
// GEMM1: proj = xn @ qkv. Tile 128x256, 256 thr (4 waves, 2Mx2N, wave tile
// 64x128), BK=32 double-buffered -> 48KB LDS -> 2 blocks/CU resident
// (reg cap 2 waves/SIMD * 2 blocks = 8 waves/CU). One block's tile-boundary
// vmcnt drain overlaps the other block's MFMA (m114). Stage for step t+1
// issued at top of step t into dead buffer. LDS: paired-row 128B lines
// (row r | row r+HALF), chunk-rotated by line&7 -> 2-way (free) frag reads;
// staging source pre-swizzled to match. grid (9, 128) = 1152 blocks.
// ---------------------------------------------------------------------------
__global__ __launch_bounds__(256, 2) void gemm_qkv_kernel(const bf16_t* __restrict__ xn,
                                                          const bf16_t* __restrict__ qkvT,
                                                          bf16_t* __restrict__ q,
                                                          bf16_t* __restrict__ kt,
                                                          bf16_t* __restrict__ vt) {
    __shared__ bf16_t smem[24576];   // 48KB: dbuf x (A 8KB | B 16KB)
    const int t = threadIdx.x, lane = t & 63, wave = t >> 6;
    const int wm = wave >> 1, wn = wave & 1;
    const int m16 = lane & 15, quad = lane >> 4;

    // XCD swizzle: 1152 blocks = 8 * 144, bijective.
    const int lb = blockIdx.y * 9 + blockIdx.x;
    const int id = (lb & 7) * 144 + (lb >> 3);
    const int tx = id % 9, ty = id / 9;
    const int mBase = ty * 128, nBase = tx * 256;

    // Staging descriptors: 6 x gld16/thread/step (A 2, B 4).
    // A chunk c -> line l=c>>3, slot s=c&7, logical lg=(s-(l&7))&7,
    // row = l + (lg>>2)*64, colchunk = lg&3. B: row = l + (lg>>2)*128.
    const bf16_t* gsrc[6];
    int ldst[6];
#pragma unroll
    for (int j = 0; j < 2; ++j) {
        int c = t + 256 * j;
        int l = c >> 3, lg = ((c & 7) - (l & 7)) & 7;
        gsrc[j] = xn + (size_t)(mBase + l + (lg >> 2) * 64) * 768 + (lg & 3) * 8;
        ldst[j] = c * 8;
    }
#pragma unroll
    for (int j = 0; j < 4; ++j) {
        int c = t + 256 * j;
        int l = c >> 3, lg = ((c & 7) - (l & 7)) & 7;
        gsrc[2 + j] = qkvT + (size_t)(nBase + l + (lg >> 2) * 128) * 768 + (lg & 3) * 8;
        ldst[2 + j] = 4096 + c * 8;
    }

    // Fragment read offsets (elements). A line = mf*16+m16 (half=wm),
    // B line = nf*16+m16 (half=wn); phys = (half*4+quad + (line&7))&7.
    int aOff[4], bOff[8];
#pragma unroll
    for (int mf = 0; mf < 4; ++mf)
        aOff[mf] = (mf * 16 + m16) * 64 + (((wm * 4 + quad) + (m16 & 7)) & 7) * 8;
#pragma unroll
    for (int nf = 0; nf < 8; ++nf)
        bOff[nf] = 4096 + (nf * 16 + m16) * 64 + (((wn * 4 + quad) + (m16 & 7)) & 7) * 8;

    f32x4 acc[4][8];
    const f32x4 z = {0.f, 0.f, 0.f, 0.f};
#pragma unroll
    for (int mf = 0; mf < 4; ++mf)
#pragma unroll
        for (int nf = 0; nf < 8; ++nf) acc[mf][nf] = z;

    // prologue: stage K-step 0 into buf0
#pragma unroll
    for (int j = 0; j < 6; ++j) gld16(gsrc[j], smem + ldst[j]);
    __syncthreads();

#pragma unroll
    for (int it = 0; it < 12; ++it) {
#pragma unroll
        for (int s = 0; s < 2; ++s) {
            const int step = it * 2 + s;
            const int par = s * 12288, nxt = 12288 - par;
            if (step < 23) {
                const int kq = (step + 1) * 32;
#pragma unroll
                for (int j = 0; j < 6; ++j)
                    gld16(gsrc[j] + kq, smem + nxt + ldst[j]);
            }
            bf16x8 af[4], bf0[4], bf1[4];
#pragma unroll
            for (int mf = 0; mf < 4; ++mf)
                af[mf] = *(const bf16x8*)(smem + par + aOff[mf]);
#pragma unroll
            for (int nf = 0; nf < 4; ++nf)
                bf0[nf] = *(const bf16x8*)(smem + par + bOff[nf]);
            __builtin_amdgcn_s_setprio(1);
#pragma unroll
            for (int mf = 0; mf < 4; ++mf)
#pragma unroll
                for (int nf = 0; nf < 4; ++nf)
                    acc[mf][nf] = __builtin_amdgcn_mfma_f32_16x16x32_bf16(
                        af[mf], bf0[nf], acc[mf][nf], 0, 0, 0);
            __builtin_amdgcn_s_setprio(0);
            __builtin_amdgcn_s_barrier();
#pragma unroll
            for (int nf = 0; nf < 4; ++nf)
                bf1[nf] = *(const bf16x8*)(smem + par + bOff[4 + nf]);
            __builtin_amdgcn_s_setprio(1);
#pragma unroll
            for (int mf = 0; mf < 4; ++mf)
#pragma unroll
                for (int nf = 0; nf < 4; ++nf)
                    acc[mf][4 + nf] = __builtin_amdgcn_mfma_f32_16x16x32_bf16(
                        af[mf], bf1[nf], acc[mf][4 + nf], 0, 0, 0);
            __builtin_amdgcn_s_setprio(0);
            __syncthreads();   // drains vmcnt: stage (issued at step top) complete
        }
    }

    // ---- per-wave epilogue, private 9KB slot (64 x 72 el) ----
    bf16_t* slot = smem + wave * 4608;
    const int b = mBase >> 10, p0 = mBase & 1023;

#pragma unroll
    for (int half = 0; half < 2; ++half) {
        const int g64 = tx * 4 + wn * 2 + half;
        const int cls = g64 % 3, h = g64 / 3;
        if (cls == 0) {
            // q: row-major (B,P,768)
#pragma unroll
            for (int mf = 0; mf < 4; ++mf)
#pragma unroll
                for (int nfl = 0; nfl < 4; ++nfl)
#pragma unroll
                    for (int i = 0; i < 4; ++i)
                        slot[(mf * 16 + quad * 4 + i) * 72 + nfl * 16 + m16] =
                            (bf16_t)acc[mf][half * 4 + nfl][i];
            asm volatile("s_waitcnt lgkmcnt(0)" ::: "memory");
            __builtin_amdgcn_sched_barrier(0);
#pragma unroll
            for (int j = 0; j < 8; ++j) {
                int r = j * 8 + (lane >> 3), cc = lane & 7;
                bf16x8 val = *(const bf16x8*)(slot + r * 72 + cc * 8);
                *(bf16x8*)(q + ((size_t)(b * 1024 + p0 + wm * 64 + r)) * 768 +
                           h * 64 + cc * 8) = val;
            }
        } else {
            // k/v: transposed (B,H,64,P) via per-wave [c][72] transpose
            bf16_t* dst = (cls == 1) ? kt : vt;
            const size_t bh = (size_t)(b * 12 + h);
#pragma unroll
            for (int mf = 0; mf < 4; ++mf)
#pragma unroll
                for (int nfl = 0; nfl < 4; ++nfl) {
                    int c = nfl * 16 + m16;
                    union { bf16_t hh[4]; uint2 u; } pk;
#pragma unroll
                    for (int i = 0; i < 4; ++i)
                        pk.hh[i] = (bf16_t)acc[mf][half * 4 + nfl][i];
                    *(uint2*)(slot + c * 72 + mf * 16 + quad * 4) = pk.u;
                }
            asm volatile("s_waitcnt lgkmcnt(0)" ::: "memory");
            __builtin_amdgcn_sched_barrier(0);
#pragma unroll
            for (int j = 0; j < 8; ++j) {
                int c = (lane >> 3) + j * 8, r8 = (lane & 7) * 8;
                bf16x8 val = *(const bf16x8*)(slot + c * 72 + r8);
                *(bf16x8*)(dst + (bh * 64 + c) * 1024 + p0 + wm * 64 + r8) = val;
            }
        }
        if (half == 0) {
            asm volatile("s_waitcnt lgkmcnt(0)" ::: "memory");
            __builtin_amdgcn_sched_barrier(0);
        }
    }
}

// ---------------------------------------------------------------------------
// T_h = K^T V per head: T[d1][d2] = sum_p K[p][d1] V[p][d2], from kt/vt
// (B,H,DH,P). Split-K over 4 waves, fp32 LDS reduce, bf16 hi/lo out.
// grid (192).
// ---------------------------------------------------------------------------
__global__ __launch_bounds__(256) void kv_kernel(const bf16_t* __restrict__ kt,
                                                 const bf16_t* __restrict__ vt,
                                                 bf16_t* __restrict__ thi,
                                                 bf16_t* __restrict__ tlo) {
    __shared__ float red[4 * 64 * 65];   // 66.6 KB
    const int bh = blockIdx.x;
    const bf16_t* Kb = kt + (size_t)bh * DH * PP;
    const bf16_t* Vb = vt + (size_t)bh * DH * PP;
    const int t = threadIdx.x;
    const int lane = t & 63, wave = t >> 6;
    const int m16 = lane & 15, quad = lane >> 4;
    const f32x4 z = {0.f, 0.f, 0.f, 0.f};
    f32x4 acc[4][4];
#pragma unroll
    for (int mm = 0; mm < 4; ++mm)
#pragma unroll
        for (int nn = 0; nn < 4; ++nn) acc[mm][nn] = z;

    for (int ks = 0; ks < 8; ++ks) {
        int kb = wave * 256 + ks * 32 + quad * 8;
        bf16x8 af[4], bfv[4];
#pragma unroll
        for (int mm = 0; mm < 4; ++mm)
            af[mm] = *(const bf16x8*)(Kb + (size_t)(mm * 16 + m16) * PP + kb);
#pragma unroll
        for (int nn = 0; nn < 4; ++nn)
            bfv[nn] = *(const bf16x8*)(Vb + (size_t)(nn * 16 + m16) * PP + kb);
#pragma unroll
        for (int mm = 0; mm < 4; ++mm)
#pragma unroll
            for (int nn = 0; nn < 4; ++nn)
                acc[mm][nn] = __builtin_amdgcn_mfma_f32_16x16x32_bf16(
                    af[mm], bfv[nn], acc[mm][nn], 0, 0, 0);
    }
#pragma unroll
    for (int mm = 0; mm < 4; ++mm)
#pragma unroll
        for (int nn = 0; nn < 4; ++nn)
#pragma unroll
            for (int i = 0; i < 4; ++i)
                red[wave * 4160 + (mm * 16 + quad * 4 + i) * 65 + nn * 16 + m16] =
                    acc[mm][nn][i];
    __syncthreads();
#pragma unroll
    for (int j = 0; j < 16; ++j) {
        int idx = j * 256 + t;            // = d1*64 + d2
        int m = idx >> 6, n = idx & 63;
        int a = m * 65 + n;
        float s = red[a] + red[4160 + a] + red[8320 + a] + red[12480 + a];
        bf16_t hi = (bf16_t)s;
        float lo = s - (float)hi;
        thi[(size_t)bh * 4096 + idx] = hi;
        tlo[(size_t)bh * 4096 + idx] = (bf16_t)lo;
    }
}

// ---------------------------------------------------------------------------
// U^b[h*64+d1][e] = sum_d2 T_h[d1][d2] * lin_w[h*64+d2][e], stored TRANSPOSED
// as Ut[b][e][h*64+d1] (bf16) so it is the Bt operand of the final GEMM.
// T enters as hi/lo (no extra rounding). grid (192, 3), 256 thr.
// ---------------------------------------------------------------------------
__global__ __launch_bounds__(256) void u_kernel(const bf16_t* __restrict__ thi,
                                                const bf16_t* __restrict__ tlo,
                                                const bf16_t* __restrict__ lwT,
                                                bf16_t* __restrict__ ut) {
    const int bh = blockIdx.x;
    const int b = bh / NH, h = bh - b * NH;
    const int nBase = blockIdx.y * 256;
    const bf16_t* Th = thi + (size_t)bh * 4096;
    const bf16_t* Tl = tlo + (size_t)bh * 4096;
    const int t = threadIdx.x, lane = t & 63, wave = t >> 6;
    const int wm = wave >> 1, wn = wave & 1;
    const int m16 = lane & 15, quad = lane >> 4;
    const f32x4 z = {0.f, 0.f, 0.f, 0.f};
    f32x4 acc[2][8];
#pragma unroll
    for (int mm = 0; mm < 2; ++mm)
#pragma unroll
        for (int nn = 0; nn < 8; ++nn) acc[mm][nn] = z;

#pragma unroll
    for (int ks = 0; ks < 2; ++ks) {
        bf16x8 ah[2], al[2], bfr[8];
#pragma unroll
        for (int mm = 0; mm < 2; ++mm) {
            ah[mm] = *(const bf16x8*)(Th + (wm * 32 + mm * 16 + m16) * 64 + ks * 32 + quad * 8);
            al[mm] = *(const bf16x8*)(Tl + (wm * 32 + mm * 16 + m16) * 64 + ks * 32 + quad * 8);
        }
#pragma unroll
        for (int nn = 0; nn < 8; ++nn)
            bfr[nn] = *(const bf16x8*)(
                lwT + (size_t)(nBase + wn * 128 + nn * 16 + m16) * 768 + h * 64 + ks * 32 + quad * 8);
#pragma unroll
        for (int mm = 0; mm < 2; ++mm)
#pragma unroll
            for (int nn = 0; nn < 8; ++nn) {
                acc[mm][nn] = __builtin_amdgcn_mfma_f32_16x16x32_bf16(
                    ah[mm], bfr[nn], acc[mm][nn], 0, 0, 0);
                acc[mm][nn] = __builtin_amdgcn_mfma_f32_16x16x32_bf16(
                    al[mm], bfr[nn], acc[mm][nn], 0, 0, 0);
            }
    }
#pragma unroll
    for (int mm = 0; mm < 2; ++mm)
#pragma unroll
        for (int nn = 0; nn < 8; ++nn) {
            int e  = nBase + wn * 128 + nn * 16 + m16;
            int d1 = wm * 32 + mm * 16 + quad * 4;
            union { bf16_t hh[4]; uint2 u; } pk;
#pragma unroll
            for (int i = 0; i < 4; ++i) pk.hh[i] = (bf16_t)acc[mm][nn][i];
            *(uint2*)(ut + ((size_t)b * 768 + e) * 768 + h * 64 + d1) = pk.u;
        }
}

// ---------------------------------------------------------------------------
// Final GEMM: out = relu(q @ U^b + lin_b) + x  (fp32 out). grid (6, 128).
// XCD-aware swizzle (T1): 768 % 8 == 0 -> bijective.
// ---------------------------------------------------------------------------
__global__ __launch_bounds__(256) void gemm_out_kernel(const bf16_t* __restrict__ q,
                                                       const bf16_t* __restrict__ ut,
                                                       const float* __restrict__ linb,
                                                       const float* __restrict__ x,
                                                       float* __restrict__ out) {
    __shared__ bf16_t smem[16384];
    f32x4 acc[4][4];
    const int lb  = blockIdx.y * 6 + blockIdx.x;    // hw linear id (x fastest)
    const int swz = (lb & 7) * 96 + (lb >> 3);      // 768/8 = 96 per XCD
    const int tx  = swz % 6, ty = swz / 6;
    const int mBase = ty * 128, nBase = tx * 128;
    const int b = mBase >> 10;
    gemm_core_128<768>(q, ut + (size_t)b * 768 * 768, mBase, nBase, acc,
                       smem, smem + 8192);

    const int lane = threadIdx.x & 63, wave = threadIdx.x >> 6;
    const int wm = wave >> 1, wn = wave & 1;
    const int m16 = lane & 15, quad = lane >> 4;
#pragma unroll
    for (int mm = 0; mm < 4; ++mm) {
#pragma unroll
        for (int i = 0; i < 4; ++i) {
            size_t row = mBase + wm * 64 + mm * 16 + quad * 4 + i;
#pragma unroll
            for (int nn = 0; nn < 4; ++nn) {
                int col = nBase + wn * 64 + nn * 16 + m16;
                float v = acc[mm][nn][i] + linb[col];
                v = fmaxf(v, 0.f) + x[row * EE + col];
                out[row * EE + col] = v;
            }
        }
    }
}

// ---------------------------------------------------------------------------
// Launch
// ---------------------------------------------------------------------------
extern "C" void kernel_launch(void* const* d_in, const int* in_sizes, int n_in,
                              void* d_out, int out_size, void* d_ws, size_t ws_size,
                              hipStream_t stream) {
    const float* x    = (const float*)d_in[0];
    const float* lnw  = (const float*)d_in[1];
    const float* lnb  = (const float*)d_in[2];
    const float* qkvw = (const float*)d_in[3];
    const float* linw = (const float*)d_in[4];
    const float* linb = (const float*)d_in[5];
    float* out = (float*)d_out;
    char* ws = (char*)d_ws;

    // Workspace layout (bytes), total ~105.4 MB. Rotation:
    //   qkvT dead after gemm_qkv -> thi/tlo ; kt dead after kv -> Ut
    float*  part  = (float*)(ws + 0);          //  8192 B
    float*  stats = (float*)(ws + 8192);       //   128 B
    bf16_t* xn    = (bf16_t*)(ws + 8448);      //  25165824 B
    bf16_t* qkvT  = (bf16_t*)(ws + 25174272);  //   3538944 B
    bf16_t* lwT   = (bf16_t*)(ws + 28713216);  //   1179648 B
    bf16_t* q     = (bf16_t*)(ws + 29892864);  //  25165824 B  (B,P,HID)
    bf16_t* kt    = (bf16_t*)(ws + 55058688);  //  25165824 B
    bf16_t* vt    = (bf16_t*)(ws + 80224512);  //  25165824 B -> end 105390336
    bf16_t* thi   = qkvT;                      // 1572864 B
    bf16_t* tlo   = qkvT + 192 * 4096;         // 1572864 B
    bf16_t* ut    = kt;                        // 18874368 B (kt dead after kv)

    stats1_kernel<<<dim3(BB * 64), dim3(256), 0, stream>>>(x, part);
    prep_kernel<<<dim3(577), dim3(256), 0, stream>>>(qkvw, linw, part, qkvT, lwT, stats);
    ln_apply_kernel<<<dim3(6144), dim3(256), 0, stream>>>(x, lnw, lnb, stats, xn);
    gemm_qkv_kernel<<<dim3(9, 128), dim3(256), 0, stream>>>(xn, qkvT, q, kt, vt);
    kv_kernel<<<dim3(192), dim3(256), 0, stream>>>(kt, vt, thi, tlo);
    u_kernel<<<dim3(192, 3), dim3(256), 0, stream>>>(thi, tlo, lwT, ut);
    gemm_out_kernel<<<dim3(6, 128), dim3(256), 0, stream>>>(q, ut, linb, x, out);
}

// Round 4
// 257.081 us; speedup vs baseline: 1.0151x; 1.0151x over previous
//
#include <hip/hip_runtime.h>
#include <hip/hip_bf16.h>
#include <cstdint>

// Problem constants
#define BB   16
#define PP   1024
#define EE   768
#define HID  768
#define NH   12
#define DH   64
#define NPB  (PP * EE)          // 786432 elements per batch
#define MROWS (BB * PP)         // 16384

typedef __bf16 bf16_t;
typedef __bf16 bf16x8 __attribute__((ext_vector_type(8)));
typedef float  f32x4  __attribute__((ext_vector_type(4)));

// Async global->LDS 16B DMA. LDS dest must be wave-uniform base + lane*16.
__device__ __forceinline__ void gld16(const void* g, void* l) {
    __builtin_amdgcn_global_load_lds(
        (const __attribute__((address_space(1))) void*)(uintptr_t)g,
        (__attribute__((address_space(3))) void*)(uint32_t)(uintptr_t)l,
        16, 0, 0);
}

// ---------------------------------------------------------------------------
// Stage 1: per-slice partial sums for batch-global LayerNorm stats
// ---------------------------------------------------------------------------
__global__ __launch_bounds__(256) void stats1_kernel(const float* __restrict__ x,
                                                     float* __restrict__ part) {
    int bid = blockIdx.x;
    int b = bid >> 6, s = bid & 63;
    const float4* xp = (const float4*)(x + (size_t)b * NPB + (size_t)s * 12288);
    float sum = 0.f, ss = 0.f;
#pragma unroll
    for (int i = 0; i < 12; ++i) {
        float4 v = xp[i * 256 + threadIdx.x];
        sum += v.x + v.y + v.z + v.w;
        ss  += v.x * v.x + v.y * v.y + v.z * v.z + v.w * v.w;
    }
#pragma unroll
    for (int off = 32; off > 0; off >>= 1) {
        sum += __shfl_down(sum, off, 64);
        ss  += __shfl_down(ss,  off, 64);
    }
    __shared__ float tmp[8];
    int wave = threadIdx.x >> 6, lane = threadIdx.x & 63;
    if (lane == 0) { tmp[wave * 2] = sum; tmp[wave * 2 + 1] = ss; }
    __syncthreads();
    if (threadIdx.x == 0) {
        part[bid * 2]     = tmp[0] + tmp[2] + tmp[4] + tmp[6];
        part[bid * 2 + 1] = tmp[1] + tmp[3] + tmp[5] + tmp[7];
    }
}

// ---------------------------------------------------------------------------
// prep: LDS-tiled weight transposes (coalesced both sides) + stats finalize.
// blocks [0,432): qkvT tiles ; [432,576): lwT tiles ; 576: stats2.
// ---------------------------------------------------------------------------
__global__ __launch_bounds__(256) void prep_kernel(const float* __restrict__ qkvw,
                                                   const float* __restrict__ linw,
                                                   const float* __restrict__ part,
                                                   bf16_t* __restrict__ qkvT,
                                                   bf16_t* __restrict__ lwT,
                                                   float* __restrict__ stats) {
    int bid = blockIdx.x;
    if (bid < 576) {
        __shared__ float lds[64][65];
        const float* src; bf16_t* dst; int r0, c0, W;
        if (bid < 432) {
            int tr = bid / 36, tc = bid - tr * 36;
            r0 = tr * 64; c0 = tc * 64; src = qkvw; W = 2304; dst = qkvT;
        } else {
            int bb = bid - 432;
            int tr = bb / 12, tc = bb - tr * 12;
            r0 = tr * 64; c0 = tc * 64; src = linw; W = 768; dst = lwT;
        }
        int t = threadIdx.x;
        int rr = t >> 4, cc4 = (t & 15) * 4;
#pragma unroll
        for (int j = 0; j < 4; ++j) {
            float4 v = *(const float4*)(src + (size_t)(r0 + rr + j * 16) * W + c0 + cc4);
            lds[rr + j * 16][cc4 + 0] = v.x;
            lds[rr + j * 16][cc4 + 1] = v.y;
            lds[rr + j * 16][cc4 + 2] = v.z;
            lds[rr + j * 16][cc4 + 3] = v.w;
        }
        __syncthreads();
        int cl = t >> 3, rgl = (t & 7) * 8;
#pragma unroll
        for (int jj = 0; jj < 2; ++jj) {
            int c = jj * 32 + cl;
            union { bf16_t h[8]; uint4 u; } o;
#pragma unroll
            for (int k = 0; k < 8; ++k) o.h[k] = (bf16_t)lds[rgl + k][c];
            *(uint4*)(dst + (size_t)(c0 + c) * 768 + r0 + rgl) = o.u;
        }
    } else {
        int wave = threadIdx.x >> 6, lane = threadIdx.x & 63;
#pragma unroll
        for (int j = 0; j < 4; ++j) {
            int b = wave * 4 + j;
            float sum = part[(b * 64 + lane) * 2];
            float ss  = part[(b * 64 + lane) * 2 + 1];
#pragma unroll
            for (int off = 32; off > 0; off >>= 1) {
                sum += __shfl_down(sum, off, 64);
                ss  += __shfl_down(ss,  off, 64);
            }
            if (lane == 0) {
                const float inv_n = 1.f / (float)NPB;
                float mean = sum * inv_n;
                float var  = ss * inv_n - mean * mean;
                stats[b * 2]     = mean;
                stats[b * 2 + 1] = rsqrtf(var + 1e-5f);
            }
        }
    }
}

__global__ __launch_bounds__(256) void ln_apply_kernel(const float* __restrict__ x,
                                                       const float* __restrict__ lnw,
                                                       const float* __restrict__ lnb,
                                                       const float* __restrict__ stats,
                                                       bf16_t* __restrict__ xn) {
    int i = (blockIdx.x * 256 + threadIdx.x) * 8;
    int b = i / NPB;
    int r = i - b * NPB;
    float mean = stats[b * 2], rstd = stats[b * 2 + 1];
    float4 x0 = *(const float4*)(x + i),     x1 = *(const float4*)(x + i + 4);
    float4 w0 = *(const float4*)(lnw + r),   w1 = *(const float4*)(lnw + r + 4);
    float4 c0 = *(const float4*)(lnb + r),   c1 = *(const float4*)(lnb + r + 4);
    union { bf16_t h[8]; uint4 u; } o;
    o.h[0] = (bf16_t)((x0.x - mean) * rstd * w0.x + c0.x);
    o.h[1] = (bf16_t)((x0.y - mean) * rstd * w0.y + c0.y);
    o.h[2] = (bf16_t)((x0.z - mean) * rstd * w0.z + c0.z);
    o.h[3] = (bf16_t)((x0.w - mean) * rstd * w0.w + c0.w);
    o.h[4] = (bf16_t)((x1.x - mean) * rstd * w1.x + c1.x);
    o.h[5] = (bf16_t)((x1.y - mean) * rstd * w1.y + c1.y);
    o.h[6] = (bf16_t)((x1.z - mean) * rstd * w1.z + c1.z);
    o.h[7] = (bf16_t)((x1.w - mean) * rstd * w1.w + c1.w);
    *(uint4*)(xn + i) = o.u;
}

// ---------------------------------------------------------------------------
// Core 128x128 GEMM tile (kept for gemm_out), BK=64, DMA staging.
// ---------------------------------------------------------------------------
template <int KDIM>
__device__ __forceinline__ void gemm_core_128(const bf16_t* __restrict__ A,
                                              const bf16_t* __restrict__ Bt,
                                              int mBase, int nBase,
                                              f32x4 acc[4][4],
                                              bf16_t* As, bf16_t* Bs) {
    const int t = threadIdx.x;
    const int lane = t & 63, wave = t >> 6;
    const int wm = wave >> 1, wn = wave & 1;
    const int m16 = lane & 15, quad = lane >> 4;

    const int sr = t >> 3, s8 = t & 7;
    const bf16_t* pa[4]; const bf16_t* pb[4];
#pragma unroll
    for (int i = 0; i < 4; ++i) {
        int row = i * 32 + sr;
        int g = (s8 - (row & 7)) & 7;
        pa[i] = A  + (size_t)(mBase + row) * KDIM + g * 8;
        pb[i] = Bt + (size_t)(nBase + row) * KDIM + g * 8;
    }

    int raOff[4][2], rbOff[4][2];
#pragma unroll
    for (int i = 0; i < 4; ++i) {
        int ra = wm * 64 + i * 16 + m16;
        int rb = wn * 64 + i * 16 + m16;
#pragma unroll
        for (int ks = 0; ks < 2; ++ks) {
            raOff[i][ks] = ra * 64 + (((ks * 4 + quad) + (ra & 7)) & 7) * 8;
            rbOff[i][ks] = rb * 64 + (((ks * 4 + quad) + (rb & 7)) & 7) * 8;
        }
    }

    const f32x4 z = {0.f, 0.f, 0.f, 0.f};
#pragma unroll
    for (int mm = 0; mm < 4; ++mm)
#pragma unroll
        for (int nn = 0; nn < 4; ++nn) acc[mm][nn] = z;

    for (int k0 = 0; k0 < KDIM; k0 += 64) {
        __syncthreads();
#pragma unroll
        for (int i = 0; i < 4; ++i) {
            gld16(pa[i] + k0, As + i * 2048 + t * 8);
            gld16(pb[i] + k0, Bs + i * 2048 + t * 8);
        }
        __syncthreads();
#pragma unroll
        for (int ks = 0; ks < 2; ++ks) {
            bf16x8 af[4], bfv[4];
#pragma unroll
            for (int i = 0; i < 4; ++i) {
                af[i]  = *(const bf16x8*)(As + raOff[i][ks]);
                bfv[i] = *(const bf16x8*)(Bs + rbOff[i][ks]);
            }
#pragma unroll
            for (int mm = 0; mm < 4; ++mm)
#pragma unroll
                for (int nn = 0; nn < 4; ++nn)
                    acc[mm][nn] = __builtin_amdgcn_mfma_f32_16x16x32_bf16(
                        af[mm], bfv[nn], acc[mm][nn], 0, 0, 0);
        }
    }
}

// ---------------------------------------------------------------------------
// GEMM1: proj = xn @ qkv. Tile 128x256, 4 waves (2Mx2N), BK=32, TRIPLE-
// buffered (72KB LDS, 2 blocks/CU) with counted vmcnt (T4): stage(t+2)
// issued at top of step t; buf[t] gated by vmcnt(12) -> 12 newer loads stay
// in flight, ~2 full steps of latency budget, no vmcnt(0) drain in the loop.
// BARRIER_A (after lgkmcnt(0) fence) guarantees step t-1's ds_reads retired
// before stage(t+2) overwrites buf[(t-1)%3]; BARRIER_B after the counted
// vmcnt guarantees all waves' slices of buf[t] landed. grid (9,128), 256 thr.
// ---------------------------------------------------------------------------
__global__ __launch_bounds__(256, 2) void gemm_qkv_kernel(const bf16_t* __restrict__ xn,
                                                          const bf16_t* __restrict__ qkvT,
                                                          bf16_t* __restrict__ q,
                                                          bf16_t* __restrict__ kt,
                                                          bf16_t* __restrict__ vt) {
    __shared__ bf16_t smem[36864];   // 72KB: 3 x (A 8KB | B 16KB)
    const int t = threadIdx.x, lane = t & 63, wave = t >> 6;
    const int wm = wave >> 1, wn = wave & 1;
    const int m16 = lane & 15, quad = lane >> 4;

    // XCD swizzle: 1152 blocks = 8 * 144, bijective.
    const int lb = blockIdx.y * 9 + blockIdx.x;
    const int id = (lb & 7) * 144 + (lb >> 3);
    const int tx = id % 9, ty = id / 9;
    const int mBase = ty * 128, nBase = tx * 256;

    // Staging descriptors: 6 x gld16/thread/step (A 2, B 4).
    // A chunk c -> line l=c>>3, slot s=c&7, logical lg=(s-(l&7))&7,
    // row = l + (lg>>2)*64, colchunk = lg&3. B: row = l + (lg>>2)*128.
    const bf16_t* gsrc[6];
    int ldst[6];
#pragma unroll
    for (int j = 0; j < 2; ++j) {
        int c = t + 256 * j;
        int l = c >> 3, lg = ((c & 7) - (l & 7)) & 7;
        gsrc[j] = xn + (size_t)(mBase + l + (lg >> 2) * 64) * 768 + (lg & 3) * 8;
        ldst[j] = c * 8;
    }
#pragma unroll
    for (int j = 0; j < 4; ++j) {
        int c = t + 256 * j;
        int l = c >> 3, lg = ((c & 7) - (l & 7)) & 7;
        gsrc[2 + j] = qkvT + (size_t)(nBase + l + (lg >> 2) * 128) * 768 + (lg & 3) * 8;
        ldst[2 + j] = 4096 + c * 8;
    }

    // Fragment read offsets (elements, relative to buffer base).
    int aOff[4], bOff[8];
#pragma unroll
    for (int mf = 0; mf < 4; ++mf)
        aOff[mf] = (mf * 16 + m16) * 64 + (((wm * 4 + quad) + (m16 & 7)) & 7) * 8;
#pragma unroll
    for (int nf = 0; nf < 8; ++nf)
        bOff[nf] = 4096 + (nf * 16 + m16) * 64 + (((wn * 4 + quad) + (m16 & 7)) & 7) * 8;

    f32x4 acc[4][8];
    const f32x4 z = {0.f, 0.f, 0.f, 0.f};
#pragma unroll
    for (int mf = 0; mf < 4; ++mf)
#pragma unroll
        for (int nf = 0; nf < 8; ++nf) acc[mf][nf] = z;

    // prologue: stage steps 0 and 1 into bufs 0,1 (12 loads in flight)
#pragma unroll
    for (int j = 0; j < 6; ++j) gld16(gsrc[j], smem + ldst[j]);
#pragma unroll
    for (int j = 0; j < 6; ++j) gld16(gsrc[j] + 32, smem + 12288 + ldst[j]);

#pragma unroll
    for (int step = 0; step < 24; ++step) {
        const int cur = (step % 3) * 12288;
        // BARRIER_A: prev step's ds_reads retired (lgkm fence) in all waves
        asm volatile("s_waitcnt lgkmcnt(0)" ::: "memory");
        __builtin_amdgcn_sched_barrier(0);
        __builtin_amdgcn_s_barrier();
        if (step + 2 < 24) {
            const int nb = ((step + 2) % 3) * 12288;
            const int kq = (step + 2) * 32;
#pragma unroll
            for (int j = 0; j < 6; ++j)
                gld16(gsrc[j] + kq, smem + nb + ldst[j]);
        }
        // counted wait for my stage(step); newer stages stay in flight
        if (step < 22)       asm volatile("s_waitcnt vmcnt(12)" ::: "memory");
        else if (step == 22) asm volatile("s_waitcnt vmcnt(6)"  ::: "memory");
        else                 asm volatile("s_waitcnt vmcnt(0)"  ::: "memory");
        __builtin_amdgcn_sched_barrier(0);
        __builtin_amdgcn_s_barrier();    // BARRIER_B: buf[step] globally ready

        bf16x8 af[4], bf0[4], bf1[4];
#pragma unroll
        for (int mf = 0; mf < 4; ++mf)
            af[mf] = *(const bf16x8*)(smem + cur + aOff[mf]);
#pragma unroll
        for (int nf = 0; nf < 4; ++nf)
            bf0[nf] = *(const bf16x8*)(smem + cur + bOff[nf]);
        __builtin_amdgcn_s_setprio(1);
#pragma unroll
        for (int mf = 0; mf < 4; ++mf)
#pragma unroll
            for (int nf = 0; nf < 4; ++nf)
                acc[mf][nf] = __builtin_amdgcn_mfma_f32_16x16x32_bf16(
                    af[mf], bf0[nf], acc[mf][nf], 0, 0, 0);
        __builtin_amdgcn_s_setprio(0);
        __builtin_amdgcn_s_barrier();    // mid-step phase barrier
#pragma unroll
        for (int nf = 0; nf < 4; ++nf)
            bf1[nf] = *(const bf16x8*)(smem + cur + bOff[4 + nf]);
        __builtin_amdgcn_s_setprio(1);
#pragma unroll
        for (int mf = 0; mf < 4; ++mf)
#pragma unroll
            for (int nf = 0; nf < 4; ++nf)
                acc[mf][4 + nf] = __builtin_amdgcn_mfma_f32_16x16x32_bf16(
                    af[mf], bf1[nf], acc[mf][4 + nf], 0, 0, 0);
        __builtin_amdgcn_s_setprio(0);
    }

    // ---- per-wave epilogue, private 9KB slot (64 x 72 el); slots occupy
    // bufs 0/1 only, disjoint from step-23 readers (buf 2). ----
    asm volatile("s_waitcnt lgkmcnt(0)" ::: "memory");
    __builtin_amdgcn_sched_barrier(0);
    bf16_t* slot = smem + wave * 4608;
    const int b = mBase >> 10, p0 = mBase & 1023;

#pragma unroll
    for (int half = 0; half < 2; ++half) {
        const int g64 = tx * 4 + wn * 2 + half;
        const int cls = g64 % 3, h = g64 / 3;
        if (cls == 0) {
            // q: row-major (B,P,768)
#pragma unroll
            for (int mf = 0; mf < 4; ++mf)
#pragma unroll
                for (int nfl = 0; nfl < 4; ++nfl)
#pragma unroll
                    for (int i = 0; i < 4; ++i)
                        slot[(mf * 16 + quad * 4 + i) * 72 + nfl * 16 + m16] =
                            (bf16_t)acc[mf][half * 4 + nfl][i];
            asm volatile("s_waitcnt lgkmcnt(0)" ::: "memory");
            __builtin_amdgcn_sched_barrier(0);
#pragma unroll
            for (int j = 0; j < 8; ++j) {
                int r = j * 8 + (lane >> 3), cc = lane & 7;
                bf16x8 val = *(const bf16x8*)(slot + r * 72 + cc * 8);
                *(bf16x8*)(q + ((size_t)(b * 1024 + p0 + wm * 64 + r)) * 768 +
                           h * 64 + cc * 8) = val;
            }
        } else {
            // k/v: transposed (B,H,64,P) via per-wave [c][72] transpose
            bf16_t* dst = (cls == 1) ? kt : vt;
            const size_t bh = (size_t)(b * 12 + h);
#pragma unroll
            for (int mf = 0; mf < 4; ++mf)
#pragma unroll
                for (int nfl = 0; nfl < 4; ++nfl) {
                    int c = nfl * 16 + m16;
                    union { bf16_t hh[4]; uint2 u; } pk;
#pragma unroll
                    for (int i = 0; i < 4; ++i)
                        pk.hh[i] = (bf16_t)acc[mf][half * 4 + nfl][i];
                    *(uint2*)(slot + c * 72 + mf * 16 + quad * 4) = pk.u;
                }
            asm volatile("s_waitcnt lgkmcnt(0)" ::: "memory");
            __builtin_amdgcn_sched_barrier(0);
#pragma unroll
            for (int j = 0; j < 8; ++j) {
                int c = (lane >> 3) + j * 8, r8 = (lane & 7) * 8;
                bf16x8 val = *(const bf16x8*)(slot + c * 72 + r8);
                *(bf16x8*)(dst + (bh * 64 + c) * 1024 + p0 + wm * 64 + r8) = val;
            }
        }
        if (half == 0) {
            asm volatile("s_waitcnt lgkmcnt(0)" ::: "memory");
            __builtin_amdgcn_sched_barrier(0);
        }
    }
}

// ---------------------------------------------------------------------------
// T_h = K^T V per head: T[d1][d2] = sum_p K[p][d1] V[p][d2], from kt/vt
// (B,H,DH,P). Split-K over 4 waves, fp32 LDS reduce, bf16 hi/lo out.
// grid (192).
// ---------------------------------------------------------------------------
__global__ __launch_bounds__(256) void kv_kernel(const bf16_t* __restrict__ kt,
                                                 const bf16_t* __restrict__ vt,
                                                 bf16_t* __restrict__ thi,
                                                 bf16_t* __restrict__ tlo) {
    __shared__ float red[4 * 64 * 65];   // 66.6 KB
    const int bh = blockIdx.x;
    const bf16_t* Kb = kt + (size_t)bh * DH * PP;
    const bf16_t* Vb = vt + (size_t)bh * DH * PP;
    const int t = threadIdx.x;
    const int lane = t & 63, wave = t >> 6;
    const int m16 = lane & 15, quad = lane >> 4;
    const f32x4 z = {0.f, 0.f, 0.f, 0.f};
    f32x4 acc[4][4];
#pragma unroll
    for (int mm = 0; mm < 4; ++mm)
#pragma unroll
        for (int nn = 0; nn < 4; ++nn) acc[mm][nn] = z;

    for (int ks = 0; ks < 8; ++ks) {
        int kb = wave * 256 + ks * 32 + quad * 8;
        bf16x8 af[4], bfv[4];
#pragma unroll
        for (int mm = 0; mm < 4; ++mm)
            af[mm] = *(const bf16x8*)(Kb + (size_t)(mm * 16 + m16) * PP + kb);
#pragma unroll
        for (int nn = 0; nn < 4; ++nn)
            bfv[nn] = *(const bf16x8*)(Vb + (size_t)(nn * 16 + m16) * PP + kb);
#pragma unroll
        for (int mm = 0; mm < 4; ++mm)
#pragma unroll
            for (int nn = 0; nn < 4; ++nn)
                acc[mm][nn] = __builtin_amdgcn_mfma_f32_16x16x32_bf16(
                    af[mm], bfv[nn], acc[mm][nn], 0, 0, 0);
    }
#pragma unroll
    for (int mm = 0; mm < 4; ++mm)
#pragma unroll
        for (int nn = 0; nn < 4; ++nn)
#pragma unroll
            for (int i = 0; i < 4; ++i)
                red[wave * 4160 + (mm * 16 + quad * 4 + i) * 65 + nn * 16 + m16] =
                    acc[mm][nn][i];
    __syncthreads();
#pragma unroll
    for (int j = 0; j < 16; ++j) {
        int idx = j * 256 + t;            // = d1*64 + d2
        int m = idx >> 6, n = idx & 63;
        int a = m * 65 + n;
        float s = red[a] + red[4160 + a] + red[8320 + a] + red[12480 + a];
        bf16_t hi = (bf16_t)s;
        float lo = s - (float)hi;
        thi[(size_t)bh * 4096 + idx] = hi;
        tlo[(size_t)bh * 4096 + idx] = (bf16_t)lo;
    }
}

// ---------------------------------------------------------------------------
// U^b[h*64+d1][e] = sum_d2 T_h[d1][d2] * lin_w[h*64+d2][e], stored TRANSPOSED
// as Ut[b][e][h*64+d1] (bf16) so it is the Bt operand of the final GEMM.
// T enters as hi/lo (no extra rounding). grid (192, 3), 256 thr.
// ---------------------------------------------------------------------------
__global__ __launch_bounds__(256) void u_kernel(const bf16_t* __restrict__ thi,
                                                const bf16_t* __restrict__ tlo,
                                                const bf16_t* __restrict__ lwT,
                                                bf16_t* __restrict__ ut) {
    const int bh = blockIdx.x;
    const int b = bh / NH, h = bh - b * NH;
    const int nBase = blockIdx.y * 256;
    const bf16_t* Th = thi + (size_t)bh * 4096;
    const bf16_t* Tl = tlo + (size_t)bh * 4096;
    const int t = threadIdx.x, lane = t & 63, wave = t >> 6;
    const int wm = wave >> 1, wn = wave & 1;
    const int m16 = lane & 15, quad = lane >> 4;
    const f32x4 z = {0.f, 0.f, 0.f, 0.f};
    f32x4 acc[2][8];
#pragma unroll
    for (int mm = 0; mm < 2; ++mm)
#pragma unroll
        for (int nn = 0; nn < 8; ++nn) acc[mm][nn] = z;

#pragma unroll
    for (int ks = 0; ks < 2; ++ks) {
        bf16x8 ah[2], al[2], bfr[8];
#pragma unroll
        for (int mm = 0; mm < 2; ++mm) {
            ah[mm] = *(const bf16x8*)(Th + (wm * 32 + mm * 16 + m16) * 64 + ks * 32 + quad * 8);
            al[mm] = *(const bf16x8*)(Tl + (wm * 32 + mm * 16 + m16) * 64 + ks * 32 + quad * 8);
        }
#pragma unroll
        for (int nn = 0; nn < 8; ++nn)
            bfr[nn] = *(const bf16x8*)(
                lwT + (size_t)(nBase + wn * 128 + nn * 16 + m16) * 768 + h * 64 + ks * 32 + quad * 8);
#pragma unroll
        for (int mm = 0; mm < 2; ++mm)
#pragma unroll
            for (int nn = 0; nn < 8; ++nn) {
                acc[mm][nn] = __builtin_amdgcn_mfma_f32_16x16x32_bf16(
                    ah[mm], bfr[nn], acc[mm][nn], 0, 0, 0);
                acc[mm][nn] = __builtin_amdgcn_mfma_f32_16x16x32_bf16(
                    al[mm], bfr[nn], acc[mm][nn], 0, 0, 0);
            }
    }
#pragma unroll
    for (int mm = 0; mm < 2; ++mm)
#pragma unroll
        for (int nn = 0; nn < 8; ++nn) {
            int e  = nBase + wn * 128 + nn * 16 + m16;
            int d1 = wm * 32 + mm * 16 + quad * 4;
            union { bf16_t hh[4]; uint2 u; } pk;
#pragma unroll
            for (int i = 0; i < 4; ++i) pk.hh[i] = (bf16_t)acc[mm][nn][i];
            *(uint2*)(ut + ((size_t)b * 768 + e) * 768 + h * 64 + d1) = pk.u;
        }
}

// ---------------------------------------------------------------------------
// Final GEMM: out = relu(q @ U^b + lin_b) + x  (fp32 out). grid (6, 128).
// XCD-aware swizzle (T1): 768 % 8 == 0 -> bijective.
// ---------------------------------------------------------------------------
__global__ __launch_bounds__(256) void gemm_out_kernel(const bf16_t* __restrict__ q,
                                                       const bf16_t* __restrict__ ut,
                                                       const float* __restrict__ linb,
                                                       const float* __restrict__ x,
                                                       float* __restrict__ out) {
    __shared__ bf16_t smem[16384];
    f32x4 acc[4][4];
    const int lb  = blockIdx.y * 6 + blockIdx.x;    // hw linear id (x fastest)
    const int swz = (lb & 7) * 96 + (lb >> 3);      // 768/8 = 96 per XCD
    const int tx  = swz % 6, ty = swz / 6;
    const int mBase = ty * 128, nBase = tx * 128;
    const int b = mBase >> 10;
    gemm_core_128<768>(q, ut + (size_t)b * 768 * 768, mBase, nBase, acc,
                       smem, smem + 8192);

    const int lane = threadIdx.x & 63, wave = threadIdx.x >> 6;
    const int wm = wave >> 1, wn = wave & 1;
    const int m16 = lane & 15, quad = lane >> 4;
#pragma unroll
    for (int mm = 0; mm < 4; ++mm) {
#pragma unroll
        for (int i = 0; i < 4; ++i) {
            size_t row = mBase + wm * 64 + mm * 16 + quad * 4 + i;
#pragma unroll
            for (int nn = 0; nn < 4; ++nn) {
                int col = nBase + wn * 64 + nn * 16 + m16;
                float v = acc[mm][nn][i] + linb[col];
                v = fmaxf(v, 0.f) + x[row * EE + col];
                out[row * EE + col] = v;
            }
        }
    }
}

// ---------------------------------------------------------------------------
// Launch
// ---------------------------------------------------------------------------
extern "C" void kernel_launch(void* const* d_in, const int* in_sizes, int n_in,
                              void* d_out, int out_size, void* d_ws, size_t ws_size,
                              hipStream_t stream) {
    const float* x    = (const float*)d_in[0];
    const float* lnw  = (const float*)d_in[1];
    const float* lnb  = (const float*)d_in[2];
    const float* qkvw = (const float*)d_in[3];
    const float* linw = (const float*)d_in[4];
    const float* linb = (const float*)d_in[5];
    float* out = (float*)d_out;
    char* ws = (char*)d_ws;

    // Workspace layout (bytes), total ~105.4 MB. Rotation:
    //   qkvT dead after gemm_qkv -> thi/tlo ; kt dead after kv -> Ut
    float*  part  = (float*)(ws + 0);          //  8192 B
    float*  stats = (float*)(ws + 8192);       //   128 B
    bf16_t* xn    = (bf16_t*)(ws + 8448);      //  25165824 B
    bf16_t* qkvT  = (bf16_t*)(ws + 25174272);  //   3538944 B
    bf16_t* lwT   = (bf16_t*)(ws + 28713216);  //   1179648 B
    bf16_t* q     = (bf16_t*)(ws + 29892864);  //  25165824 B  (B,P,HID)
    bf16_t* kt    = (bf16_t*)(ws + 55058688);  //  25165824 B
    bf16_t* vt    = (bf16_t*)(ws + 80224512);  //  25165824 B -> end 105390336
    bf16_t* thi   = qkvT;                      // 1572864 B
    bf16_t* tlo   = qkvT + 192 * 4096;         // 1572864 B
    bf16_t* ut    = kt;                        // 18874368 B (kt dead after kv)

    stats1_kernel<<<dim3(BB * 64), dim3(256), 0, stream>>>(x, part);
    prep_kernel<<<dim3(577), dim3(256), 0, stream>>>(qkvw, linw, part, qkvT, lwT, stats);
    ln_apply_kernel<<<dim3(6144), dim3(256), 0, stream>>>(x, lnw, lnb, stats, xn);
    gemm_qkv_kernel<<<dim3(9, 128), dim3(256), 0, stream>>>(xn, qkvT, q, kt, vt);
    kv_kernel<<<dim3(192), dim3(256), 0, stream>>>(kt, vt, thi, tlo);
    u_kernel<<<dim3(192, 3), dim3(256), 0, stream>>>(thi, tlo, lwT, ut);
    gemm_out_kernel<<<dim3(6, 128), dim3(256), 0, stream>>>(q, ut, linb, x, out);
}

// Round 5
// 251.928 us; speedup vs baseline: 1.0359x; 1.0205x over previous
//
#include <hip/hip_runtime.h>
#include <hip/hip_bf16.h>
#include <cstdint>

// Problem constants
#define BB   16
#define PP   1024
#define EE   768
#define HID  768
#define NH   12
#define DH   64
#define NPB  (PP * EE)          // 786432 elements per batch
#define MROWS (BB * PP)         // 16384

typedef __bf16 bf16_t;
typedef __bf16 bf16x8 __attribute__((ext_vector_type(8)));
typedef float  f32x4  __attribute__((ext_vector_type(4)));

// Async global->LDS 16B DMA. LDS dest must be wave-uniform base + lane*16.
__device__ __forceinline__ void gld16(const void* g, void* l) {
    __builtin_amdgcn_global_load_lds(
        (const __attribute__((address_space(1))) void*)(uintptr_t)g,
        (__attribute__((address_space(3))) void*)(uint32_t)(uintptr_t)l,
        16, 0, 0);
}

// ---------------------------------------------------------------------------
// Stage 1: per-slice partial sums for batch-global LayerNorm stats
// ---------------------------------------------------------------------------
__global__ __launch_bounds__(256) void stats1_kernel(const float* __restrict__ x,
                                                     float* __restrict__ part) {
    int bid = blockIdx.x;
    int b = bid >> 6, s = bid & 63;
    const float4* xp = (const float4*)(x + (size_t)b * NPB + (size_t)s * 12288);
    float sum = 0.f, ss = 0.f;
#pragma unroll
    for (int i = 0; i < 12; ++i) {
        float4 v = xp[i * 256 + threadIdx.x];
        sum += v.x + v.y + v.z + v.w;
        ss  += v.x * v.x + v.y * v.y + v.z * v.z + v.w * v.w;
    }
#pragma unroll
    for (int off = 32; off > 0; off >>= 1) {
        sum += __shfl_down(sum, off, 64);
        ss  += __shfl_down(ss,  off, 64);
    }
    __shared__ float tmp[8];
    int wave = threadIdx.x >> 6, lane = threadIdx.x & 63;
    if (lane == 0) { tmp[wave * 2] = sum; tmp[wave * 2 + 1] = ss; }
    __syncthreads();
    if (threadIdx.x == 0) {
        part[bid * 2]     = tmp[0] + tmp[2] + tmp[4] + tmp[6];
        part[bid * 2 + 1] = tmp[1] + tmp[3] + tmp[5] + tmp[7];
    }
}

// ---------------------------------------------------------------------------
// prep: LDS-tiled weight transposes (coalesced both sides) + stats finalize.
// blocks [0,432): qkvT tiles ; [432,576): lwT tiles ; 576: stats2.
// ---------------------------------------------------------------------------
__global__ __launch_bounds__(256) void prep_kernel(const float* __restrict__ qkvw,
                                                   const float* __restrict__ linw,
                                                   const float* __restrict__ part,
                                                   bf16_t* __restrict__ qkvT,
                                                   bf16_t* __restrict__ lwT,
                                                   float* __restrict__ stats) {
    int bid = blockIdx.x;
    if (bid < 576) {
        __shared__ float lds[64][65];
        const float* src; bf16_t* dst; int r0, c0, W;
        if (bid < 432) {
            int tr = bid / 36, tc = bid - tr * 36;
            r0 = tr * 64; c0 = tc * 64; src = qkvw; W = 2304; dst = qkvT;
        } else {
            int bb = bid - 432;
            int tr = bb / 12, tc = bb - tr * 12;
            r0 = tr * 64; c0 = tc * 64; src = linw; W = 768; dst = lwT;
        }
        int t = threadIdx.x;
        int rr = t >> 4, cc4 = (t & 15) * 4;
#pragma unroll
        for (int j = 0; j < 4; ++j) {
            float4 v = *(const float4*)(src + (size_t)(r0 + rr + j * 16) * W + c0 + cc4);
            lds[rr + j * 16][cc4 + 0] = v.x;
            lds[rr + j * 16][cc4 + 1] = v.y;
            lds[rr + j * 16][cc4 + 2] = v.z;
            lds[rr + j * 16][cc4 + 3] = v.w;
        }
        __syncthreads();
        int cl = t >> 3, rgl = (t & 7) * 8;
#pragma unroll
        for (int jj = 0; jj < 2; ++jj) {
            int c = jj * 32 + cl;
            union { bf16_t h[8]; uint4 u; } o;
#pragma unroll
            for (int k = 0; k < 8; ++k) o.h[k] = (bf16_t)lds[rgl + k][c];
            *(uint4*)(dst + (size_t)(c0 + c) * 768 + r0 + rgl) = o.u;
        }
    } else {
        int wave = threadIdx.x >> 6, lane = threadIdx.x & 63;
#pragma unroll
        for (int j = 0; j < 4; ++j) {
            int b = wave * 4 + j;
            float sum = part[(b * 64 + lane) * 2];
            float ss  = part[(b * 64 + lane) * 2 + 1];
#pragma unroll
            for (int off = 32; off > 0; off >>= 1) {
                sum += __shfl_down(sum, off, 64);
                ss  += __shfl_down(ss,  off, 64);
            }
            if (lane == 0) {
                const float inv_n = 1.f / (float)NPB;
                float mean = sum * inv_n;
                float var  = ss * inv_n - mean * mean;
                stats[b * 2]     = mean;
                stats[b * 2 + 1] = rsqrtf(var + 1e-5f);
            }
        }
    }
}

__global__ __launch_bounds__(256) void ln_apply_kernel(const float* __restrict__ x,
                                                       const float* __restrict__ lnw,
                                                       const float* __restrict__ lnb,
                                                       const float* __restrict__ stats,
                                                       bf16_t* __restrict__ xn) {
    int i = (blockIdx.x * 256 + threadIdx.x) * 8;
    int b = i / NPB;
    int r = i - b * NPB;
    float mean = stats[b * 2], rstd = stats[b * 2 + 1];
    float4 x0 = *(const float4*)(x + i),     x1 = *(const float4*)(x + i + 4);
    float4 w0 = *(const float4*)(lnw + r),   w1 = *(const float4*)(lnw + r + 4);
    float4 c0 = *(const float4*)(lnb + r),   c1 = *(const float4*)(lnb + r + 4);
    union { bf16_t h[8]; uint4 u; } o;
    o.h[0] = (bf16_t)((x0.x - mean) * rstd * w0.x + c0.x);
    o.h[1] = (bf16_t)((x0.y - mean) * rstd * w0.y + c0.y);
    o.h[2] = (bf16_t)((x0.z - mean) * rstd * w0.z + c0.z);
    o.h[3] = (bf16_t)((x0.w - mean) * rstd * w0.w + c0.w);
    o.h[4] = (bf16_t)((x1.x - mean) * rstd * w1.x + c1.x);
    o.h[5] = (bf16_t)((x1.y - mean) * rstd * w1.y + c1.y);
    o.h[6] = (bf16_t)((x1.z - mean) * rstd * w1.z + c1.z);
    o.h[7] = (bf16_t)((x1.w - mean) * rstd * w1.w + c1.w);
    *(uint4*)(xn + i) = o.u;
}

// ---------------------------------------------------------------------------
// Shared core: 128x128 tile, BK=32, TRIPLE-buffered (48KB -> 3 blocks/CU,
// 3 waves/SIMD), counted vmcnt(8) (2 steps of in-flight distance), 4 waves
// (2Mx2N, wave tile 64x64). LDS lines 128B = paired rows (r | r+64), chunk
// slot rotated by line&7 (2-way free); staging source pre-swizzled to match.
// Per step: 4 gld16 + 8 ds_read_b128 + 16 MFMA + 2 barriers.
// ---------------------------------------------------------------------------
__device__ __forceinline__ void core128_bk32(const bf16_t* __restrict__ A,
                                             const bf16_t* __restrict__ Bt,
                                             int mBase, int nBase,
                                             f32x4 acc[4][4], bf16_t* smem) {
    const int t = threadIdx.x, lane = t & 63, wave = t >> 6;
    const int wm = wave >> 1, wn = wave & 1;
    const int m16 = lane & 15, quad = lane >> 4;

    // staging: chunk c -> line l=c>>3, slot s=c&7, logical lg=(s-(l&7))&7,
    // row = l + (lg>>2)*64, colchunk = lg&3.
    const bf16_t* gsrc[4];
    int ldst[4];
#pragma unroll
    for (int j = 0; j < 2; ++j) {
        int c = t + 256 * j;
        int l = c >> 3, lg = ((c & 7) - (l & 7)) & 7;
        int row = l + (lg >> 2) * 64, kc = lg & 3;
        gsrc[j]     = A  + (size_t)(mBase + row) * 768 + kc * 8;
        ldst[j]     = c * 8;
        gsrc[2 + j] = Bt + (size_t)(nBase + row) * 768 + kc * 8;
        ldst[2 + j] = 4096 + c * 8;
    }

    int aOff[4], bOff[4];
#pragma unroll
    for (int f = 0; f < 4; ++f) {
        aOff[f] = (f * 16 + m16) * 64 + (((wm * 4 + quad) + (m16 & 7)) & 7) * 8;
        bOff[f] = 4096 + (f * 16 + m16) * 64 + (((wn * 4 + quad) + (m16 & 7)) & 7) * 8;
    }

    const f32x4 z = {0.f, 0.f, 0.f, 0.f};
#pragma unroll
    for (int mf = 0; mf < 4; ++mf)
#pragma unroll
        for (int nf = 0; nf < 4; ++nf) acc[mf][nf] = z;

    // prologue: stage steps 0,1 into bufs 0,1
#pragma unroll
    for (int j = 0; j < 4; ++j) gld16(gsrc[j], smem + ldst[j]);
#pragma unroll
    for (int j = 0; j < 4; ++j) gld16(gsrc[j] + 32, smem + 8192 + ldst[j]);

#pragma unroll
    for (int step = 0; step < 24; ++step) {
        const int cur = (step % 3) * 8192;
        // BARRIER_A: prior step's ds_reads retired in all waves before
        // stage(step+2) overwrites buf[(step-1)%3]
        asm volatile("s_waitcnt lgkmcnt(0)" ::: "memory");
        __builtin_amdgcn_sched_barrier(0);
        __builtin_amdgcn_s_barrier();
        if (step + 2 < 24) {
            const int nb = ((step + 2) % 3) * 8192;
            const int kq = (step + 2) * 32;
#pragma unroll
            for (int j = 0; j < 4; ++j)
                gld16(gsrc[j] + kq, smem + nb + ldst[j]);
        }
        // counted wait: stage(step) done, stages step+1/step+2 in flight
        if (step < 22)       asm volatile("s_waitcnt vmcnt(8)" ::: "memory");
        else if (step == 22) asm volatile("s_waitcnt vmcnt(4)" ::: "memory");
        else                 asm volatile("s_waitcnt vmcnt(0)" ::: "memory");
        __builtin_amdgcn_sched_barrier(0);
        __builtin_amdgcn_s_barrier();    // BARRIER_B: buf[step] globally ready

        bf16x8 af[4], bfv[4];
#pragma unroll
        for (int f = 0; f < 4; ++f) {
            af[f]  = *(const bf16x8*)(smem + cur + aOff[f]);
            bfv[f] = *(const bf16x8*)(smem + cur + bOff[f]);
        }
        __builtin_amdgcn_s_setprio(1);
#pragma unroll
        for (int mf = 0; mf < 4; ++mf)
#pragma unroll
            for (int nf = 0; nf < 4; ++nf)
                acc[mf][nf] = __builtin_amdgcn_mfma_f32_16x16x32_bf16(
                    af[mf], bfv[nf], acc[mf][nf], 0, 0, 0);
        __builtin_amdgcn_s_setprio(0);
    }
}

// ---------------------------------------------------------------------------
// GEMM1: proj = xn @ qkv. grid (18,128) = 2304 blocks = 3 exact rounds at
// 3 blk/CU. Each wave owns one 64-col group (q slice or k/v head-slice):
// fully independent per-wave epilogues in private 9KB LDS slots.
// ---------------------------------------------------------------------------
__global__ __launch_bounds__(256, 3) void gemm_qkv_kernel(const bf16_t* __restrict__ xn,
                                                          const bf16_t* __restrict__ qkvT,
                                                          bf16_t* __restrict__ q,
                                                          bf16_t* __restrict__ kt,
                                                          bf16_t* __restrict__ vt) {
    __shared__ bf16_t smem[24576];   // 48KB: 3 x (A 8KB | B 8KB)
    const int t = threadIdx.x, lane = t & 63, wave = t >> 6;
    const int wm = wave >> 1, wn = wave & 1;
    const int m16 = lane & 15, quad = lane >> 4;

    // XCD swizzle: 2304 blocks = 8 * 288, bijective.
    const int lb = blockIdx.y * 18 + blockIdx.x;
    const int id = (lb & 7) * 288 + (lb >> 3);
    const int tx = id % 18, ty = id / 18;
    const int mBase = ty * 128, nBase = tx * 128;

    f32x4 acc[4][4];
    core128_bk32(xn, qkvT, mBase, nBase, acc, smem);

    // epilogue: wave (wm,wn) owns rows p0+wm*64..+63, cols nBase+wn*64..+63
    __syncthreads();   // step-23 readers done before slots overwrite buf2
    bf16_t* slot = smem + wave * 4608;   // 64 x 72 elements
    const int b = mBase >> 10, p0 = mBase & 1023;
    const int g64 = tx * 2 + wn;
    const int cls = g64 % 3, h = g64 / 3;

    if (cls == 0) {
        // q: row-major (B,P,768)
#pragma unroll
        for (int mf = 0; mf < 4; ++mf)
#pragma unroll
            for (int nf = 0; nf < 4; ++nf)
#pragma unroll
                for (int i = 0; i < 4; ++i)
                    slot[(mf * 16 + quad * 4 + i) * 72 + nf * 16 + m16] =
                        (bf16_t)acc[mf][nf][i];
        asm volatile("s_waitcnt lgkmcnt(0)" ::: "memory");
        __builtin_amdgcn_sched_barrier(0);
#pragma unroll
        for (int j = 0; j < 8; ++j) {
            int r = j * 8 + (lane >> 3), cc = lane & 7;
            bf16x8 val = *(const bf16x8*)(slot + r * 72 + cc * 8);
            *(bf16x8*)(q + ((size_t)(b * 1024 + p0 + wm * 64 + r)) * 768 +
                       h * 64 + cc * 8) = val;
        }
    } else {
        // k/v: transposed (B,H,64,P) via per-wave [c][72] transpose
        bf16_t* dst = (cls == 1) ? kt : vt;
        const size_t bh = (size_t)(b * 12 + h);
#pragma unroll
        for (int mf = 0; mf < 4; ++mf)
#pragma unroll
            for (int nf = 0; nf < 4; ++nf) {
                int c = nf * 16 + m16;
                union { bf16_t hh[4]; uint2 u; } pk;
#pragma unroll
                for (int i = 0; i < 4; ++i) pk.hh[i] = (bf16_t)acc[mf][nf][i];
                *(uint2*)(slot + c * 72 + mf * 16 + quad * 4) = pk.u;
            }
        asm volatile("s_waitcnt lgkmcnt(0)" ::: "memory");
        __builtin_amdgcn_sched_barrier(0);
#pragma unroll
        for (int j = 0; j < 8; ++j) {
            int c = (lane >> 3) + j * 8, r8 = (lane & 7) * 8;
            bf16x8 val = *(const bf16x8*)(slot + c * 72 + r8);
            *(bf16x8*)(dst + (bh * 64 + c) * 1024 + p0 + wm * 64 + r8) = val;
        }
    }
}

// ---------------------------------------------------------------------------
// kvu: fused T = K^T V (per head) then U = T @ lin_w slice, T never leaves
// the block. Phase A: split-K over 4 waves + fp32 LDS reduce. Phase B: each
// wave builds its T hi/lo frags from the reduce and runs the 64x768 GEMM,
// storing Ut[b][e][h*64+d1] (Bt operand of final GEMM). grid (192).
// ---------------------------------------------------------------------------
__global__ __launch_bounds__(256) void kvu_kernel(const bf16_t* __restrict__ kt,
                                                  const bf16_t* __restrict__ vt,
                                                  const bf16_t* __restrict__ lwT,
                                                  bf16_t* __restrict__ ut) {
    __shared__ float red[4 * 64 * 65];   // 66.6 KB
    const int bh = blockIdx.x;
    const int b = bh / NH, h = bh - b * NH;
    const bf16_t* Kb = kt + (size_t)bh * DH * PP;
    const bf16_t* Vb = vt + (size_t)bh * DH * PP;
    const int t = threadIdx.x;
    const int lane = t & 63, wave = t >> 6;
    const int m16 = lane & 15, quad = lane >> 4;
    const f32x4 z = {0.f, 0.f, 0.f, 0.f};

    // ---- phase A: T partials ----
    {
        f32x4 acc[4][4];
#pragma unroll
        for (int mm = 0; mm < 4; ++mm)
#pragma unroll
            for (int nn = 0; nn < 4; ++nn) acc[mm][nn] = z;
        for (int ks = 0; ks < 8; ++ks) {
            int kb = wave * 256 + ks * 32 + quad * 8;
            bf16x8 af[4], bfv[4];
#pragma unroll
            for (int mm = 0; mm < 4; ++mm)
                af[mm] = *(const bf16x8*)(Kb + (size_t)(mm * 16 + m16) * PP + kb);
#pragma unroll
            for (int nn = 0; nn < 4; ++nn)
                bfv[nn] = *(const bf16x8*)(Vb + (size_t)(nn * 16 + m16) * PP + kb);
#pragma unroll
            for (int mm = 0; mm < 4; ++mm)
#pragma unroll
                for (int nn = 0; nn < 4; ++nn)
                    acc[mm][nn] = __builtin_amdgcn_mfma_f32_16x16x32_bf16(
                        af[mm], bfv[nn], acc[mm][nn], 0, 0, 0);
        }
#pragma unroll
        for (int mm = 0; mm < 4; ++mm)
#pragma unroll
            for (int nn = 0; nn < 4; ++nn)
#pragma unroll
                for (int i = 0; i < 4; ++i)
                    red[wave * 4160 + (mm * 16 + quad * 4 + i) * 65 + nn * 16 + m16] =
                        acc[mm][nn][i];
    }
    __syncthreads();

    // ---- build T hi/lo frags (u-GEMM A operand layout) ----
    const int wm = wave >> 1, wn = wave & 1;
    bf16x8 ah[2][2], al[2][2];
#pragma unroll
    for (int mm = 0; mm < 2; ++mm)
#pragma unroll
        for (int ks = 0; ks < 2; ++ks) {
            int d1 = wm * 32 + mm * 16 + m16;
            int base = d1 * 65 + ks * 32 + quad * 8;
#pragma unroll
            for (int e = 0; e < 8; ++e) {
                float s = red[base + e] + red[4160 + base + e] +
                          red[8320 + base + e] + red[12480 + base + e];
                bf16_t hi = (bf16_t)s;
                ah[mm][ks][e] = hi;
                al[mm][ks][e] = (bf16_t)(s - (float)hi);
            }
        }

    // ---- phase B: U = T @ lwT-slice, 3 x 256-col chunks ----
#pragma unroll
    for (int ny = 0; ny < 3; ++ny) {
        const int nBase = ny * 256;
        f32x4 acc2[2][8];
#pragma unroll
        for (int mm = 0; mm < 2; ++mm)
#pragma unroll
            for (int nn = 0; nn < 8; ++nn) acc2[mm][nn] = z;
#pragma unroll
        for (int ks = 0; ks < 2; ++ks) {
            bf16x8 bfr[8];
#pragma unroll
            for (int nn = 0; nn < 8; ++nn)
                bfr[nn] = *(const bf16x8*)(
                    lwT + (size_t)(nBase + wn * 128 + nn * 16 + m16) * 768 +
                    h * 64 + ks * 32 + quad * 8);
#pragma unroll
            for (int mm = 0; mm < 2; ++mm)
#pragma unroll
                for (int nn = 0; nn < 8; ++nn) {
                    acc2[mm][nn] = __builtin_amdgcn_mfma_f32_16x16x32_bf16(
                        ah[mm][ks], bfr[nn], acc2[mm][nn], 0, 0, 0);
                    acc2[mm][nn] = __builtin_amdgcn_mfma_f32_16x16x32_bf16(
                        al[mm][ks], bfr[nn], acc2[mm][nn], 0, 0, 0);
                }
        }
#pragma unroll
        for (int mm = 0; mm < 2; ++mm)
#pragma unroll
            for (int nn = 0; nn < 8; ++nn) {
                int e  = nBase + wn * 128 + nn * 16 + m16;
                int d1 = wm * 32 + mm * 16 + quad * 4;
                union { bf16_t hh[4]; uint2 u; } pk;
#pragma unroll
                for (int i = 0; i < 4; ++i) pk.hh[i] = (bf16_t)acc2[mm][nn][i];
                *(uint2*)(ut + ((size_t)b * 768 + e) * 768 + h * 64 + d1) = pk.u;
            }
    }
}

// ---------------------------------------------------------------------------
// Final GEMM: out = relu(q @ U^b + lin_b) + x (fp32 out). grid (6,128) = 768
// blocks = 3 exact rounds at 3 blk/CU. Same BK=32 counted-vmcnt core.
// ---------------------------------------------------------------------------
__global__ __launch_bounds__(256, 3) void gemm_out_kernel(const bf16_t* __restrict__ q,
                                                          const bf16_t* __restrict__ ut,
                                                          const float* __restrict__ linb,
                                                          const float* __restrict__ x,
                                                          float* __restrict__ out) {
    __shared__ bf16_t smem[24576];
    const int lb  = blockIdx.y * 6 + blockIdx.x;
    const int swz = (lb & 7) * 96 + (lb >> 3);      // 768/8 = 96 per XCD
    const int tx  = swz % 6, ty = swz / 6;
    const int mBase = ty * 128, nBase = tx * 128;
    const int b = mBase >> 10;

    f32x4 acc[4][4];
    core128_bk32(q, ut + (size_t)b * 768 * 768, mBase, nBase, acc, smem);

    const int lane = threadIdx.x & 63, wave = threadIdx.x >> 6;
    const int wm = wave >> 1, wn = wave & 1;
    const int m16 = lane & 15, quad = lane >> 4;
#pragma unroll
    for (int mm = 0; mm < 4; ++mm) {
#pragma unroll
        for (int i = 0; i < 4; ++i) {
            size_t row = mBase + wm * 64 + mm * 16 + quad * 4 + i;
#pragma unroll
            for (int nn = 0; nn < 4; ++nn) {
                int col = nBase + wn * 64 + nn * 16 + m16;
                float v = acc[mm][nn][i] + linb[col];
                v = fmaxf(v, 0.f) + x[row * EE + col];
                out[row * EE + col] = v;
            }
        }
    }
}

// ---------------------------------------------------------------------------
// Launch
// ---------------------------------------------------------------------------
extern "C" void kernel_launch(void* const* d_in, const int* in_sizes, int n_in,
                              void* d_out, int out_size, void* d_ws, size_t ws_size,
                              hipStream_t stream) {
    const float* x    = (const float*)d_in[0];
    const float* lnw  = (const float*)d_in[1];
    const float* lnb  = (const float*)d_in[2];
    const float* qkvw = (const float*)d_in[3];
    const float* linw = (const float*)d_in[4];
    const float* linb = (const float*)d_in[5];
    float* out = (float*)d_out;
    char* ws = (char*)d_ws;

    // Workspace layout (bytes), total ~105.4 MB. Rotation:
    //   xn dead after gemm_qkv -> ut lives there (kvu reads kt/vt while
    //   writing ut, so ut must NOT alias kt/vt).
    float*  part  = (float*)(ws + 0);          //  8192 B
    float*  stats = (float*)(ws + 8192);       //   128 B
    bf16_t* xn    = (bf16_t*)(ws + 8448);      //  25165824 B
    bf16_t* qkvT  = (bf16_t*)(ws + 25174272);  //   3538944 B
    bf16_t* lwT   = (bf16_t*)(ws + 28713216);  //   1179648 B
    bf16_t* q     = (bf16_t*)(ws + 29892864);  //  25165824 B  (B,P,HID)
    bf16_t* kt    = (bf16_t*)(ws + 55058688);  //  25165824 B
    bf16_t* vt    = (bf16_t*)(ws + 80224512);  //  25165824 B -> end 105390336
    bf16_t* ut    = xn;                        //  18874368 B (xn dead after qkv)

    stats1_kernel<<<dim3(BB * 64), dim3(256), 0, stream>>>(x, part);
    prep_kernel<<<dim3(577), dim3(256), 0, stream>>>(qkvw, linw, part, qkvT, lwT, stats);
    ln_apply_kernel<<<dim3(6144), dim3(256), 0, stream>>>(x, lnw, lnb, stats, xn);
    gemm_qkv_kernel<<<dim3(18, 128), dim3(256), 0, stream>>>(xn, qkvT, q, kt, vt);
    kvu_kernel<<<dim3(192), dim3(256), 0, stream>>>(kt, vt, lwT, ut);
    gemm_out_kernel<<<dim3(6, 128), dim3(256), 0, stream>>>(q, ut, linb, x, out);
}